// Round 11
// baseline (418.970 us; speedup 1.0000x reference)
//
#include <hip/hip_runtime.h>

// SelfAttentionBlock: x[8,2048,512]; Wq/Wk/Wv [512,512]; bq/bk/bv [512].
// out[8,2048,1024] = concat(x, causal_softmax(QK^T/sqrt(512)) @ V).
// v19: on v18 (256.2us): combine_k FUSED into attn_k via last-finisher
// device-scope atomic (stream-K fixup pattern): writer does threadfence +
// atomicAdd(cnt[pair]); the block seeing old==1 combines its 64 rows.
// Removes the 4096-block combine launch and overlaps combine with attn.
// cnt[256] zeroed by prep_k (stream-ordered, per-replay). prep/proj
// otherwise unchanged from v18. attn main loop byte-identical (at the
// 256-VGPR ceiling -- epilogue-only addition).

#define DEV __device__ __forceinline__

typedef unsigned short u16;
typedef unsigned int u32;
typedef __attribute__((ext_vector_type(8))) short short8;   // 8 bf16 = 4 VGPRs
typedef __attribute__((ext_vector_type(4))) float float4v;  // MFMA C/D frag

DEV u16 f2bf(float f) {
    u32 u = __float_as_uint(f);
    return (u16)((u + 0x7FFFu + ((u >> 16) & 1u)) >> 16);
}
DEV float bf2f(u16 h) { return __uint_as_float(((u32)h) << 16); }

DEV float4v mfma16(short8 a, short8 b, float4v c) {
    return __builtin_amdgcn_mfma_f32_16x16x32_bf16(a, b, c, 0, 0, 0);
}

// async global->LDS, 16B per lane; LDS dest = wave-uniform base + lane*16
#define GLD16(gptr, lptr)                                                     \
    __builtin_amdgcn_global_load_lds(                                         \
        (const __attribute__((address_space(1))) void*)(gptr),                \
        (__attribute__((address_space(3))) void*)(lptr), 16, 0, 0)

// ---------------- Kernel 1: fused prep (detect + convx + convW + bias) ------
__global__ void prep_k(const void* __restrict__ x,
                       const void* __restrict__ Wq, const void* __restrict__ Wk,
                       const void* __restrict__ Wv, const void* __restrict__ bq,
                       const void* __restrict__ bk, const void* __restrict__ bv,
                       int* __restrict__ flag, u16* __restrict__ xb,
                       void* __restrict__ out, u16* __restrict__ Wt,
                       u16* __restrict__ bbuf, int* __restrict__ cnt) {
    __shared__ __attribute__((aligned(16))) u16 T[64 * 80];   // 10 KB, pad 80
    int tid = threadIdx.x;
    int lane = tid & 63;
    u32 ws = ((const u32*)x)[lane * 16];
    int e = (ws >> 7) & 0xFF;
    unsigned long long m = __ballot(e >= 0x60 && e <= 0x90);
    int isbf = (__popcll(m) > 32) ? 1 : 0;   // 1 = bf16 input

    int bid = blockIdx.x;
    if (bid == 0 && tid == 0) flag[0] = isbf;

    if (bid < 4096) {                         // ---- x part ----
        int i0 = (bid * 256 + tid) * 8;
        int row = i0 >> 9, col = i0 & 511;
        if (isbf) {
            uint4 v = *(const uint4*)((const u16*)x + i0);
            *(uint4*)&xb[i0] = v;
            *(uint4*)((u16*)out + (size_t)row * 1024 + col) = v;
        } else {
            const float* xf = (const float*)x;
            float4 f0 = *(const float4*)(xf + i0);
            float4 f1 = *(const float4*)(xf + i0 + 4);
            union { u16 us[8]; uint4 v; } pk;
            pk.us[0] = f2bf(f0.x); pk.us[1] = f2bf(f0.y);
            pk.us[2] = f2bf(f0.z); pk.us[3] = f2bf(f0.w);
            pk.us[4] = f2bf(f1.x); pk.us[5] = f2bf(f1.y);
            pk.us[6] = f2bf(f1.z); pk.us[7] = f2bf(f1.w);
            *(uint4*)&xb[i0] = pk.v;
            float* o = (float*)out + (size_t)row * 1024 + col;
            *(float4*)o = f0; *(float4*)(o + 4) = f1;
        }
        return;
    }

    if (bid >= 4288) {                        // ---- bias part (+cnt zero) ----
        int j = bid - 4288;
        if (j == 0) cnt[tid] = 0;             // zero split-K pair counters
        int z = j >> 1;
        int i = (j & 1) * 256 + tid;          // 0..511
        const void* s = (z == 0) ? bq : ((z == 1) ? bk : bv);
        bbuf[z * 512 + i] = isbf ? ((const u16*)s)[i]
                                 : f2bf(((const float*)s)[i]);
        return;
    }

    // ---- W transpose part: tile (k0,n0) 64x64 -> Wt[z][n][k] ----
    int widx = bid - 4096;                    // 0..191
    int z = widx >> 6;
    int t64 = widx & 63;
    int k0 = (t64 >> 3) * 64, n0 = (t64 & 7) * 64;
    const void* W = (z == 0) ? Wq : ((z == 1) ? Wk : Wv);
    if (isbf) {
        #pragma unroll
        for (int p = 0; p < 2; p++) {
            int idx = p * 256 + tid;          // 0..511
            int k = idx >> 3, c8 = idx & 7;
            short8 v = *(const short8*)((const u16*)W + (size_t)(k0 + k) * 512 + n0 + c8 * 8);
            #pragma unroll
            for (int j = 0; j < 8; j++)
                T[(c8 * 8 + j) * 80 + k] = (u16)v[j];
        }
    } else {
        #pragma unroll
        for (int p = 0; p < 4; p++) {
            int idx = p * 256 + tid;          // 0..1023
            int k = idx >> 4, c4 = idx & 15;
            float4 f = *(const float4*)((const float*)W + (size_t)(k0 + k) * 512 + n0 + c4 * 4);
            T[(c4 * 4 + 0) * 80 + k] = f2bf(f.x);
            T[(c4 * 4 + 1) * 80 + k] = f2bf(f.y);
            T[(c4 * 4 + 2) * 80 + k] = f2bf(f.z);
            T[(c4 * 4 + 3) * 80 + k] = f2bf(f.w);
        }
    }
    __syncthreads();
    #pragma unroll
    for (int p = 0; p < 2; p++) {
        int idx = p * 256 + tid;              // 0..511
        int n = idx >> 3, c8 = idx & 7;
        short8 o = *(const short8*)&T[n * 80 + c8 * 8];
        *(uint4*)&Wt[z * 262144 + (size_t)(n0 + n) * 512 + k0 + c8 * 8] = *(uint4*)&o;
    }
}

// counted wait + raw barrier (keeps prefetch loads in flight across barrier)
#define PWB(N)                                                                \
    do {                                                                      \
        asm volatile("s_waitcnt vmcnt(" #N ")" ::: "memory");                 \
        __builtin_amdgcn_s_barrier();                                         \
        asm volatile("" ::: "memory");                                        \
    } while (0)

// ---------------- Kernel 4: QKV projection GEMM (v17) -----------------------
// 1-D XCD-swizzled grid: the 12 blocks sharing an X-panel map to one XCD.
__global__ __launch_bounds__(256) void proj_k(
        const u16* __restrict__ x, const u16* __restrict__ Wt,
        const u16* __restrict__ bb,
        u16* __restrict__ Qo, u16* __restrict__ Ko, u16* __restrict__ Vt_out) {
    int L = blockIdx.x;                       // 0..1535
    int xcd = L & 7;
    int t8 = L >> 3;                          // 0..191
    int q8 = t8 / 12;                         // 0..15  (m / 8)
    int zn = t8 - q8 * 12;                    // 0..11
    int mBase = (q8 * 8 + xcd) * 128;
    int z = zn >> 2;                          // 0..2
    int nBase = (zn & 3) * 128;
    const u16* Wz = Wt + z * 262144;                       // Wz[n][k]
    const u16* bias = bb + z * 512;

    __shared__ __attribute__((aligned(16))) u16 LDSBUF[16384];   // 32 KB
#define XSB(bi) (&LDSBUF[(bi) * 4096])
#define WSB(bi) (&LDSBUF[8192 + (bi) * 4096])

    int tid = threadIdx.x;
    int w = tid >> 6, lane = tid & 63, quad = lane >> 4, l16 = lane & 15;
    int wr = (w >> 1) * 64, wc = (w & 1) * 64;

#define PISSUE(bi, k0)                                                        \
    { _Pragma("unroll")                                                       \
      for (int gg = 0; gg < 2; gg++) {                                        \
        int g = w * 2 + gg;                                                   \
        int row = g * 16 + (lane >> 2);                                       \
        int c8 = (lane & 3) ^ ((row >> 1) & 3);                               \
        GLD16(&x [(size_t)(mBase + row) * 512 + (k0) + c8 * 8], &XSB(bi)[g * 512]); \
        GLD16(&Wz[(size_t)(nBase + row) * 512 + (k0) + c8 * 8], &WSB(bi)[g * 512]); \
      } }

    PISSUE(0, 0)
    PISSUE(1, 32)

    float4v acc[4][4] = {};

    #pragma unroll 2
    for (int t = 0; t < 16; t++) {
        int bi = t & 1;
        if (t < 15) { PWB(4); } else { PWB(0); }

        short8 a[4], b[4];
        #pragma unroll
        for (int mt = 0; mt < 4; mt++) {
            int rr = wr + mt * 16 + l16;
            a[mt] = *(const short8*)&XSB(bi)[rr * 32 + ((quad ^ ((rr >> 1) & 3)) * 8)];
        }
        #pragma unroll
        for (int nt = 0; nt < 4; nt++) {
            int rr = wc + nt * 16 + l16;
            b[nt] = *(const short8*)&WSB(bi)[rr * 32 + ((quad ^ ((rr >> 1) & 3)) * 8)];
        }
        #pragma unroll
        for (int mt = 0; mt < 4; mt++)
            #pragma unroll
            for (int nt = 0; nt < 4; nt++)
                acc[mt][nt] = mfma16(a[mt], b[nt], acc[mt][nt]);

        if (t < 14) {
            asm volatile("s_waitcnt lgkmcnt(0)" ::: "memory");
            __builtin_amdgcn_s_barrier();
            asm volatile("" ::: "memory");
            PISSUE(bi, (t + 2) * 32)
        }
    }

    // ---- epilogue: LDS re-stage + coalesced 16B stores ----
    __syncthreads();                      // K-loop LDS reads all done
    u16* stg = &LDSBUF[w * 4096];         // this wave's 8 KB (64x64 bf16)

    if (z == 2) {
        #pragma unroll
        for (int nt = 0; nt < 4; nt++) {
            int rl = nt * 16 + l16;                       // d_local
            float bval = bf2f(bias[nBase + wc + rl]);
            int rx = rl & 7;
            #pragma unroll
            for (int mt = 0; mt < 4; mt++) {
                int g  = mt * 2 + (quad >> 1);            // t-granule
                int b0 = (quad & 1) * 4;
                float4v v = acc[mt][nt];
                u16 t0 = f2bf(v[0] + bval), t1 = f2bf(v[1] + bval);
                u16 t2 = f2bf(v[2] + bval), t3 = f2bf(v[3] + bval);
                uint2 pk = make_uint2((u32)t0 | ((u32)t1 << 16),
                                      (u32)t2 | ((u32)t3 << 16));
                *(uint2*)&stg[rl * 64 + ((g ^ rx) << 3) + b0] = pk;
            }
        }
        asm volatile("s_waitcnt lgkmcnt(0)" ::: "memory");
        __syncthreads();
        int bbi = (mBase + wr) >> 11;
        int tt0 = (mBase + wr) & 2047;
        #pragma unroll
        for (int i = 0; i < 8; i++) {
            int rl = i * 8 + (lane >> 3);                 // d_local
            int c8 = lane & 7;                            // t-granule
            short8 s = *(const short8*)&stg[rl * 64 + ((c8 ^ (rl & 7)) << 3)];
            *(uint4*)&Vt_out[((size_t)bbi * 512 + nBase + wc + rl) * 2048 +
                             tt0 + c8 * 8] = *(uint4*)&s;
        }
    } else {
        u16* dst = (z == 0) ? Qo : Ko;
        #pragma unroll
        for (int nt = 0; nt < 4; nt++) {
            int cl = nt * 16 + l16;
            float bval = bf2f(bias[nBase + wc + cl]);
            int g = nt * 2 + (l16 >> 3);
            int b = l16 & 7;
            #pragma unroll
            for (int mt = 0; mt < 4; mt++) {
                float4v v = acc[mt][nt];
                #pragma unroll
                for (int r = 0; r < 4; r++) {
                    int rl = mt * 16 + quad * 4 + r;
                    stg[rl * 64 + ((g ^ (rl & 7)) << 3) + b] = f2bf(v[r] + bval);
                }
            }
        }
        asm volatile("s_waitcnt lgkmcnt(0)" ::: "memory");
        __syncthreads();
        #pragma unroll
        for (int i = 0; i < 8; i++) {
            int rl = i * 8 + (lane >> 3);                 // m_local
            int c8 = lane & 7;                            // n-granule
            short8 s = *(const short8*)&stg[rl * 64 + ((c8 ^ (rl & 7)) << 3)];
            *(uint4*)&dst[(size_t)(mBase + wr + rl) * 512 +
                          nBase + wc + c8 * 8] = *(uint4*)&s;
        }
    }
#undef PISSUE
#undef XSB
#undef WSB
}

// ---------------- Kernel 5: flash attention + fused split-K combine ---------
// Main loop byte-identical to v18 (256 VGPR ceiling). Epilogue A now ends
// with: threadfence -> atomicAdd(cnt[pair]) -> last finisher combines.

#define LOADK(dst, kB, half)                                                  \
    { _Pragma("unroll")                                                       \
      for (int j = 0; j < 8; j++) {                                           \
        int row2 = 2 * (j * 4 + w);                                           \
        int row = row2 + (lane >> 5);                                         \
        int col8 = lane & 31;                                                 \
        GLD16(&Kb[(size_t)((kB) + row) * 512 + (half) * 256 +                 \
                  ((col8 ^ (row & 7)) << 3)], &dst[row2 * 256]);              \
      } }

#define LOADV(dst, kB, half)                                                  \
    { _Pragma("unroll")                                                       \
      for (int j = 0; j < 8; j++) {                                           \
        int blk8 = 8 * (j * 4 + w);                                           \
        int dl = blk8 + (lane >> 3);                                          \
        int col8 = lane & 7;                                                  \
        GLD16(&Vb[(size_t)((half) * 256 + dl) * 2048 + (kB) +                 \
                  ((col8 ^ (dl & 7)) << 3)], &dst[blk8 * 64]);                \
      } }

#define SSTEP(buf, h)                                                         \
    { _Pragma("unroll")                                                       \
      for (int kk = 0; kk < 8; kk++) {                                        \
        _Pragma("unroll")                                                     \
        for (int nt = 0; nt < 4; nt++) {                                      \
          short8 bf = *(const short8*)&buf[(nt * 16 + l16) * 256 +            \
                                           (((kk * 4 + quad) ^ sw) << 3)];    \
          accS[nt] = mfma16(qf[(h) * 8 + kk], bf, accS[nt]);                  \
        } } }

#define PVSTEP(buf, accO)                                                     \
    { _Pragma("unroll")                                                       \
      for (int kk = 0; kk < 2; kk++) {                                        \
        _Pragma("unroll")                                                     \
        for (int dt = 0; dt < 4; dt++) {                                      \
          int rowv = w * 64 + dt * 16 + l16;                                  \
          short8 bf = *(const short8*)&buf[rowv * 64 +                        \
                                           (((kk * 4 + quad) ^ sw) << 3)];    \
          _Pragma("unroll")                                                   \
          for (int mt = 0; mt < 4; mt++)                                      \
            accO[dt][mt] = mfma16(pf[mt][kk], bf, accO[dt][mt]);              \
        } } }

__global__ __launch_bounds__(256, 1) void attn_k(
        const u16* __restrict__ Q, const u16* __restrict__ K,
        const u16* __restrict__ Vt, const int* __restrict__ flag,
        void* __restrict__ out, u16* __restrict__ Opart,
        float2* __restrict__ ml, int* __restrict__ cnt, int dosplit) {
    int blk = blockIdx.x;
    int b, qt, h, kt0, kt1;
    if (dosplit) {
        qt = (blk < 256) ? (31 - (blk >> 4)) : ((blk - 256) >> 4);
        h  = (blk >> 3) & 1;
        b  = blk & 7;
        int n = qt + 1, mid = n >> 1;
        kt0 = h ? mid : 0;
        kt1 = h ? n : mid;
    } else {
        qt = 31 - (blk >> 3);
        h  = 0;
        b  = blk & 7;
        kt0 = 0; kt1 = qt + 1;
    }
    int q0 = qt * 64;
    int isbf = flag[0];

    __shared__ __attribute__((aligned(16))) u16 KV0[16384];   // 32 KB
    __shared__ __attribute__((aligned(16))) u16 KV1[16384];   // 32 KB
    __shared__ __attribute__((aligned(16))) u16 Ps[4096];     // P 64x64 bf16
    __shared__ float al_s[64];
    __shared__ float il_s[64];
    __shared__ int skip_s[4];
    __shared__ int comb_s;

    int tid = threadIdx.x;
    int w = tid >> 6, lane = tid & 63, quad = lane >> 4, l16 = lane & 15;
    int sw = l16 & 7;

    const u16* Qb = Q  + (size_t)b * 2048 * 512;
    const u16* Kb = K  + (size_t)b * 2048 * 512;
    const u16* Vb = Vt + (size_t)b * 512 * 2048;

    if (kt0 < kt1) LOADK(KV0, kt0 * 64, 0);    // prefetch first K half0

    // Q fragments in regs: rows w*16+l16, qf[g] = d-granule g (static idx only)
    short8 qf[16];
    {
        const u16* Qrow = &Qb[(size_t)(q0 + w * 16 + l16) * 512];
        #pragma unroll
        for (int g = 0; g < 16; g++)
            qf[g] = *(const short8*)&Qrow[g * 32 + quad * 8];
    }

    float4v accO0[4][4] = {};     // d = 0*256 + w*64 + dt*16 + l16
    float4v accO1[4][4] = {};     // d = 1*256 + w*64 + dt*16 + l16
    float4v accS[4] = {};         // keys nt*16+l16, rows w*16+quad*4+r
    short8 pf[4][2];
    float mrow[4] = {-1e30f, -1e30f, -1e30f, -1e30f};
    float lrow[4] = {0.f, 0.f, 0.f, 0.f};   // per-lane partial sums (v18)
    const float scale = 0.044194173824159216f;     // 1/sqrt(512)

    __syncthreads();

    for (int kt = kt0; kt < kt1; kt++) {
        int kB = kt * 64;

        // ---- ph0: prefetch K half1 -> KV1; S += Q0.K0 from KV0 ----
        LOADK(KV1, kB, 1);
        SSTEP(KV0, 0);
        __syncthreads();

        // ---- ph1: prefetch V half0 -> KV0; S += Q1.K1 from KV1; softmax ----
        LOADV(KV0, kB, 0);
        SSTEP(KV1, 1);
        {
            int diag = (kt == qt);
            float pv[4][4], lmx[4], alpha[4];
            #pragma unroll
            for (int r = 0; r < 4; r++) {
                float mx = -1e30f;
                #pragma unroll
                for (int nt = 0; nt < 4; nt++) {
                    float sv = accS[nt][r] * scale;
                    if (diag && (nt * 16 + l16 > w * 16 + quad * 4 + r)) sv = -1e30f;
                    pv[nt][r] = sv;
                    mx = fmaxf(mx, sv);
                }
                lmx[r] = mx;
            }
            // defer-max (T13) v2: decide from lane-local maxes (no shuffles).
            int small = (lmx[0] - mrow[0] <= 8.f) && (lmx[1] - mrow[1] <= 8.f) &&
                        (lmx[2] - mrow[2] <= 8.f) && (lmx[3] - mrow[3] <= 8.f);
            int wskip = __all(small) ? 1 : 0;
            if (lane == 0) skip_s[w] = wskip;
            if (wskip) {
                #pragma unroll
                for (int r = 0; r < 4; r++) alpha[r] = 1.0f;
            } else {
                #pragma unroll
                for (int r = 0; r < 4; r++) {
                    float mx = lmx[r];
                    mx = fmaxf(mx, __shfl_xor(mx, 1));
                    mx = fmaxf(mx, __shfl_xor(mx, 2));
                    mx = fmaxf(mx, __shfl_xor(mx, 4));
                    mx = fmaxf(mx, __shfl_xor(mx, 8));
                    float mnew = fmaxf(mrow[r], mx);
                    alpha[r] = __expf(mrow[r] - mnew);
                    mrow[r] = mnew;
                }
            }
            // lrow = per-lane partials; butterfly deferred to epilogue (v18).
            #pragma unroll
            for (int r = 0; r < 4; r++) {
                float sum = 0.f;
                #pragma unroll
                for (int nt = 0; nt < 4; nt++) {
                    pv[nt][r] = __expf(pv[nt][r] - mrow[r]);
                    sum += pv[nt][r];
                }
                lrow[r] = lrow[r] * alpha[r] + sum;
            }
            #pragma unroll
            for (int nt = 0; nt < 4; nt++)
                #pragma unroll
                for (int r = 0; r < 4; r++)
                    Ps[(w * 16 + quad * 4 + r) * 64 + nt * 16 + l16] = f2bf(pv[nt][r]);
            #pragma unroll
            for (int r = 0; r < 4; r++) al_s[w * 16 + quad * 4 + r] = alpha[r];
            #pragma unroll
            for (int nt = 0; nt < 4; nt++) accS[nt] = (float4v){0.f, 0.f, 0.f, 0.f};
        }
        __syncthreads();

        // ---- ph2: prefetch V half1 -> KV1; P-frags (+rescale unless all
        //          waves deferred); O0 += P.V0 ----
        LOADV(KV1, kB, 1);
        {
            #pragma unroll
            for (int mt = 0; mt < 4; mt++)
                #pragma unroll
                for (int kk = 0; kk < 2; kk++)
                    pf[mt][kk] = *(const short8*)&Ps[(mt * 16 + l16) * 64 +
                                                     kk * 32 + quad * 8];
            int bskip = skip_s[0] & skip_s[1] & skip_s[2] & skip_s[3];
            if (!bskip) {
                float alf[4][4];
                #pragma unroll
                for (int mt = 0; mt < 4; mt++)
                    #pragma unroll
                    for (int r = 0; r < 4; r++)
                        alf[mt][r] = al_s[mt * 16 + quad * 4 + r];
                #pragma unroll
                for (int dt = 0; dt < 4; dt++)
                    #pragma unroll
                    for (int mt = 0; mt < 4; mt++)
                        #pragma unroll
                        for (int r = 0; r < 4; r++) {
                            accO0[dt][mt][r] *= alf[mt][r];
                            accO1[dt][mt][r] *= alf[mt][r];
                        }
            }
        }
        PVSTEP(KV0, accO0);
        __syncthreads();

        // ---- ph3: prefetch next K half0 -> KV0; O1 += P.V1 from KV1 ----
        if (kt + 1 < kt1) LOADK(KV0, kB + 64, 0);
        PVSTEP(KV1, accO1);
        __syncthreads();
    }

    // finalize lrow -- one butterfly over the 16-lane group (v18).
    #pragma unroll
    for (int r = 0; r < 4; r++) {
        lrow[r] += __shfl_xor(lrow[r], 1);
        lrow[r] += __shfl_xor(lrow[r], 2);
        lrow[r] += __shfl_xor(lrow[r], 4);
        lrow[r] += __shfl_xor(lrow[r], 8);
    }

    if (dosplit) {
        // ---- epilogue A: write unnormalized O (bf16) + per-row (m,l) ----
        if (l16 == 0) {
            #pragma unroll
            for (int r = 0; r < 4; r++) {
                int grow = b * 2048 + q0 + w * 16 + quad * 4 + r;
                ml[h * 16384 + grow] = make_float2(mrow[r], lrow[r]);
            }
        }
        #pragma unroll
        for (int dt = 0; dt < 4; dt++) {
            int dg = w * 64 + dt * 16 + l16;
            #pragma unroll
            for (int mt = 0; mt < 4; mt++)
                #pragma unroll
                for (int r = 0; r < 4; r++) {
                    int grow = b * 2048 + q0 + mt * 16 + quad * 4 + r;
                    size_t base = ((size_t)h * 16384 + grow) * 512;
                    Opart[base + dg]       = f2bf(accO0[dt][mt][r]);
                    Opart[base + dg + 256] = f2bf(accO1[dt][mt][r]);
                }
        }

        // ---- fused combine: last finisher of the (b,qt) pair ----
        __threadfence();                       // my Opart/ml visible device-wide
        __syncthreads();                       // all threads in block fenced
        if (tid == 0) {
            int old = atomicAdd(&cnt[qt * 8 + b], 1);
            comb_s = (old == 1);
        }
        __syncthreads();
        if (comb_s) {
            __threadfence();                   // acquire: see partner's writes
            u16*   o16 = (u16*)out;
            float* o32 = (float*)out;
            #pragma unroll 4
            for (int it = 0; it < 16; it++) {
                int grow = b * 2048 + q0 + it * 4 + (tid >> 6);
                int d0 = (tid & 63) * 8;
                float2 ml0 = ml[grow], ml1 = ml[16384 + grow];
                float mm = fmaxf(ml0.x, ml1.x);
                float a0 = __expf(ml0.x - mm), a1 = __expf(ml1.x - mm);
                float il = 1.0f / (ml0.y * a0 + ml1.y * a1);
                a0 *= il; a1 *= il;
                uint4 v0 = *(const uint4*)&Opart[(size_t)grow * 512 + d0];
                uint4 v1 = *(const uint4*)&Opart[(size_t)(16384 + grow) * 512 + d0];
                const u16* u0 = (const u16*)&v0;
                const u16* u1 = (const u16*)&v1;
                float res[8];
                #pragma unroll
                for (int i = 0; i < 8; i++)
                    res[i] = bf2f(u0[i]) * a0 + bf2f(u1[i]) * a1;
                size_t base = (size_t)grow * 1024 + 512 + d0;
                if (isbf) {
                    union { u16 us[8]; uint4 v; } pk;
                    #pragma unroll
                    for (int i = 0; i < 8; i++) pk.us[i] = f2bf(res[i]);
                    *(uint4*)(o16 + base) = pk.v;
                } else {
                    float* o = o32 + base;
                    *(float4*)o = make_float4(res[0], res[1], res[2], res[3]);
                    *(float4*)(o + 4) = make_float4(res[4], res[5], res[6], res[7]);
                }
            }
        }
    } else {
        // ---- epilogue B: share 1/l, normalize, write out[..., 512:1024] ----
        #pragma unroll
        for (int r = 0; r < 4; r++) il_s[w * 16 + quad * 4 + r] = 1.0f / lrow[r];
        __syncthreads();
        float invl[4][4];
        #pragma unroll
        for (int mt = 0; mt < 4; mt++)
            #pragma unroll
            for (int r = 0; r < 4; r++) invl[mt][r] = il_s[mt * 16 + quad * 4 + r];
        u16*   o16 = (u16*)out;
        float* o32 = (float*)out;
        #pragma unroll
        for (int dt = 0; dt < 4; dt++) {
            int dg0 = 512 + w * 64 + dt * 16 + l16;
            #pragma unroll
            for (int mt = 0; mt < 4; mt++)
                #pragma unroll
                for (int r = 0; r < 4; r++) {
                    int rowg = q0 + mt * 16 + quad * 4 + r;
                    size_t base = ((size_t)b * 2048 + rowg) * 1024;
                    float v0 = accO0[dt][mt][r] * invl[mt][r];
                    float v1 = accO1[dt][mt][r] * invl[mt][r];
                    if (isbf) {
                        o16[base + dg0]       = f2bf(v0);
                        o16[base + dg0 + 256] = f2bf(v1);
                    } else {
                        o32[base + dg0]       = v0;
                        o32[base + dg0 + 256] = v1;
                    }
                }
        }
    }
}

// ---------------- launcher --------------------------------------------------
extern "C" void kernel_launch(void* const* d_in, const int* in_sizes, int n_in,
                              void* d_out, int out_size, void* d_ws, size_t ws_size,
                              hipStream_t stream) {
    const void* x  = d_in[0];
    const void* Wq = d_in[1];
    const void* bq = d_in[2];
    const void* Wk = d_in[3];
    const void* bk = d_in[4];
    const void* Wv = d_in[5];
    const void* bv = d_in[6];

    u16* base = (u16*)d_ws;
    int* flag = (int*)base;                         // 16 B
    u16* Wt   = base + 8;                           // 3*512*512
    u16* bb   = Wt + 786432;                        // 1536 (pad 1544)
    u16* xb   = bb + 1544;                          // 8,388,608
    u16* Qw   = xb + 8388608;
    u16* Kw   = Qw + 8388608;
    u16* Vtw  = Kw + 8388608;                       // Vt[b][d][t]
    u16* Opart = Vtw + 8388608;                     // 2*16384*512 u16 = 33.5 MB
    float2* mlb = (float2*)(Opart + 16777216);      // 2*16384 float2 = 256 KB
    int* cnt = (int*)(mlb + 32768);                 // 256 ints = 1 KB

    size_t need = ((size_t)(Opart - base) + 16777216) * 2 + 262144 + 1024;
    int dosplit = (ws_size >= need) ? 1 : 0;

    hipLaunchKernelGGL(prep_k, dim3(4294), dim3(256), 0, stream,
                       x, Wq, Wk, Wv, bq, bk, bv, flag, xb, d_out, Wt, bb, cnt);
    hipLaunchKernelGGL(proj_k, dim3(1536), dim3(256), 0, stream, xb, Wt, bb, Qw, Kw, Vtw);
    if (dosplit) {
        hipLaunchKernelGGL(attn_k, dim3(512), dim3(256), 0, stream,
                           Qw, Kw, Vtw, flag, d_out, Opart, mlb, cnt, 1);
    } else {
        hipLaunchKernelGGL(attn_k, dim3(256), dim3(256), 0, stream,
                           Qw, Kw, Vtw, flag, d_out, Opart, mlb, cnt, 0);
    }
}

// Round 12
// 254.629 us; speedup vs baseline: 1.6454x; 1.6454x over previous
//
#include <hip/hip_runtime.h>

// SelfAttentionBlock: x[8,2048,512]; Wq/Wk/Wv [512,512]; bq/bk/bv [512].
// out[8,2048,1024] = concat(x, causal_softmax(QK^T/sqrt(512)) @ V).
// v20: REVERT to v18 (256.2us, best). v19's fused combine kept out/Opart/ml
// pointers + combine code live across the main loop -> partial spill at the
// 256-VGPR ceiling (FETCH +16MB, WRITE +37MB, same MFMA work over 2.7x time).
// LAW (3x confirmed: v9/v12/v19): attn_k main loop has ZERO register slack;
// only zero-live-state additions are safe. combine stays a separate kernel.

#define DEV __device__ __forceinline__

typedef unsigned short u16;
typedef unsigned int u32;
typedef __attribute__((ext_vector_type(8))) short short8;   // 8 bf16 = 4 VGPRs
typedef __attribute__((ext_vector_type(4))) float float4v;  // MFMA C/D frag

DEV u16 f2bf(float f) {
    u32 u = __float_as_uint(f);
    return (u16)((u + 0x7FFFu + ((u >> 16) & 1u)) >> 16);
}
DEV float bf2f(u16 h) { return __uint_as_float(((u32)h) << 16); }

DEV float4v mfma16(short8 a, short8 b, float4v c) {
    return __builtin_amdgcn_mfma_f32_16x16x32_bf16(a, b, c, 0, 0, 0);
}

// async global->LDS, 16B per lane; LDS dest = wave-uniform base + lane*16
#define GLD16(gptr, lptr)                                                     \
    __builtin_amdgcn_global_load_lds(                                         \
        (const __attribute__((address_space(1))) void*)(gptr),                \
        (__attribute__((address_space(3))) void*)(lptr), 16, 0, 0)

// ---------------- Kernel 1: fused prep (detect + convx + convW + bias) ------
__global__ void prep_k(const void* __restrict__ x,
                       const void* __restrict__ Wq, const void* __restrict__ Wk,
                       const void* __restrict__ Wv, const void* __restrict__ bq,
                       const void* __restrict__ bk, const void* __restrict__ bv,
                       int* __restrict__ flag, u16* __restrict__ xb,
                       void* __restrict__ out, u16* __restrict__ Wt,
                       u16* __restrict__ bbuf) {
    __shared__ __attribute__((aligned(16))) u16 T[64 * 80];   // 10 KB, pad 80
    int tid = threadIdx.x;
    int lane = tid & 63;
    u32 ws = ((const u32*)x)[lane * 16];
    int e = (ws >> 7) & 0xFF;
    unsigned long long m = __ballot(e >= 0x60 && e <= 0x90);
    int isbf = (__popcll(m) > 32) ? 1 : 0;   // 1 = bf16 input

    int bid = blockIdx.x;
    if (bid == 0 && tid == 0) flag[0] = isbf;

    if (bid < 4096) {                         // ---- x part ----
        int i0 = (bid * 256 + tid) * 8;
        int row = i0 >> 9, col = i0 & 511;
        if (isbf) {
            uint4 v = *(const uint4*)((const u16*)x + i0);
            *(uint4*)&xb[i0] = v;
            *(uint4*)((u16*)out + (size_t)row * 1024 + col) = v;
        } else {
            const float* xf = (const float*)x;
            float4 f0 = *(const float4*)(xf + i0);
            float4 f1 = *(const float4*)(xf + i0 + 4);
            union { u16 us[8]; uint4 v; } pk;
            pk.us[0] = f2bf(f0.x); pk.us[1] = f2bf(f0.y);
            pk.us[2] = f2bf(f0.z); pk.us[3] = f2bf(f0.w);
            pk.us[4] = f2bf(f1.x); pk.us[5] = f2bf(f1.y);
            pk.us[6] = f2bf(f1.z); pk.us[7] = f2bf(f1.w);
            *(uint4*)&xb[i0] = pk.v;
            float* o = (float*)out + (size_t)row * 1024 + col;
            *(float4*)o = f0; *(float4*)(o + 4) = f1;
        }
        return;
    }

    if (bid >= 4288) {                        // ---- bias part ----
        int j = bid - 4288;
        int z = j >> 1;
        int i = (j & 1) * 256 + tid;          // 0..511
        const void* s = (z == 0) ? bq : ((z == 1) ? bk : bv);
        bbuf[z * 512 + i] = isbf ? ((const u16*)s)[i]
                                 : f2bf(((const float*)s)[i]);
        return;
    }

    // ---- W transpose part: tile (k0,n0) 64x64 -> Wt[z][n][k] ----
    int widx = bid - 4096;                    // 0..191
    int z = widx >> 6;
    int t64 = widx & 63;
    int k0 = (t64 >> 3) * 64, n0 = (t64 & 7) * 64;
    const void* W = (z == 0) ? Wq : ((z == 1) ? Wk : Wv);
    if (isbf) {
        #pragma unroll
        for (int p = 0; p < 2; p++) {
            int idx = p * 256 + tid;          // 0..511
            int k = idx >> 3, c8 = idx & 7;
            short8 v = *(const short8*)((const u16*)W + (size_t)(k0 + k) * 512 + n0 + c8 * 8);
            #pragma unroll
            for (int j = 0; j < 8; j++)
                T[(c8 * 8 + j) * 80 + k] = (u16)v[j];
        }
    } else {
        #pragma unroll
        for (int p = 0; p < 4; p++) {
            int idx = p * 256 + tid;          // 0..1023
            int k = idx >> 4, c4 = idx & 15;
            float4 f = *(const float4*)((const float*)W + (size_t)(k0 + k) * 512 + n0 + c4 * 4);
            T[(c4 * 4 + 0) * 80 + k] = f2bf(f.x);
            T[(c4 * 4 + 1) * 80 + k] = f2bf(f.y);
            T[(c4 * 4 + 2) * 80 + k] = f2bf(f.z);
            T[(c4 * 4 + 3) * 80 + k] = f2bf(f.w);
        }
    }
    __syncthreads();
    #pragma unroll
    for (int p = 0; p < 2; p++) {
        int idx = p * 256 + tid;              // 0..511
        int n = idx >> 3, c8 = idx & 7;
        short8 o = *(const short8*)&T[n * 80 + c8 * 8];
        *(uint4*)&Wt[z * 262144 + (size_t)(n0 + n) * 512 + k0 + c8 * 8] = *(uint4*)&o;
    }
}

// counted wait + raw barrier (keeps prefetch loads in flight across barrier)
#define PWB(N)                                                                \
    do {                                                                      \
        asm volatile("s_waitcnt vmcnt(" #N ")" ::: "memory");                 \
        __builtin_amdgcn_s_barrier();                                         \
        asm volatile("" ::: "memory");                                        \
    } while (0)

// ---------------- Kernel 4: QKV projection GEMM (v17) -----------------------
// 1-D XCD-swizzled grid: the 12 blocks sharing an X-panel map to one XCD.
__global__ __launch_bounds__(256) void proj_k(
        const u16* __restrict__ x, const u16* __restrict__ Wt,
        const u16* __restrict__ bb,
        u16* __restrict__ Qo, u16* __restrict__ Ko, u16* __restrict__ Vt_out) {
    int L = blockIdx.x;                       // 0..1535
    int xcd = L & 7;
    int t8 = L >> 3;                          // 0..191
    int q8 = t8 / 12;                         // 0..15  (m / 8)
    int zn = t8 - q8 * 12;                    // 0..11
    int mBase = (q8 * 8 + xcd) * 128;
    int z = zn >> 2;                          // 0..2
    int nBase = (zn & 3) * 128;
    const u16* Wz = Wt + z * 262144;                       // Wz[n][k]
    const u16* bias = bb + z * 512;

    __shared__ __attribute__((aligned(16))) u16 LDSBUF[16384];   // 32 KB
#define XSB(bi) (&LDSBUF[(bi) * 4096])
#define WSB(bi) (&LDSBUF[8192 + (bi) * 4096])

    int tid = threadIdx.x;
    int w = tid >> 6, lane = tid & 63, quad = lane >> 4, l16 = lane & 15;
    int wr = (w >> 1) * 64, wc = (w & 1) * 64;

#define PISSUE(bi, k0)                                                        \
    { _Pragma("unroll")                                                       \
      for (int gg = 0; gg < 2; gg++) {                                        \
        int g = w * 2 + gg;                                                   \
        int row = g * 16 + (lane >> 2);                                       \
        int c8 = (lane & 3) ^ ((row >> 1) & 3);                               \
        GLD16(&x [(size_t)(mBase + row) * 512 + (k0) + c8 * 8], &XSB(bi)[g * 512]); \
        GLD16(&Wz[(size_t)(nBase + row) * 512 + (k0) + c8 * 8], &WSB(bi)[g * 512]); \
      } }

    PISSUE(0, 0)
    PISSUE(1, 32)

    float4v acc[4][4] = {};

    #pragma unroll 2
    for (int t = 0; t < 16; t++) {
        int bi = t & 1;
        if (t < 15) { PWB(4); } else { PWB(0); }

        short8 a[4], b[4];
        #pragma unroll
        for (int mt = 0; mt < 4; mt++) {
            int rr = wr + mt * 16 + l16;
            a[mt] = *(const short8*)&XSB(bi)[rr * 32 + ((quad ^ ((rr >> 1) & 3)) * 8)];
        }
        #pragma unroll
        for (int nt = 0; nt < 4; nt++) {
            int rr = wc + nt * 16 + l16;
            b[nt] = *(const short8*)&WSB(bi)[rr * 32 + ((quad ^ ((rr >> 1) & 3)) * 8)];
        }
        #pragma unroll
        for (int mt = 0; mt < 4; mt++)
            #pragma unroll
            for (int nt = 0; nt < 4; nt++)
                acc[mt][nt] = mfma16(a[mt], b[nt], acc[mt][nt]);

        if (t < 14) {
            asm volatile("s_waitcnt lgkmcnt(0)" ::: "memory");
            __builtin_amdgcn_s_barrier();
            asm volatile("" ::: "memory");
            PISSUE(bi, (t + 2) * 32)
        }
    }

    // ---- epilogue: LDS re-stage + coalesced 16B stores ----
    __syncthreads();                      // K-loop LDS reads all done
    u16* stg = &LDSBUF[w * 4096];         // this wave's 8 KB (64x64 bf16)

    if (z == 2) {
        #pragma unroll
        for (int nt = 0; nt < 4; nt++) {
            int rl = nt * 16 + l16;                       // d_local
            float bval = bf2f(bias[nBase + wc + rl]);
            int rx = rl & 7;
            #pragma unroll
            for (int mt = 0; mt < 4; mt++) {
                int g  = mt * 2 + (quad >> 1);            // t-granule
                int b0 = (quad & 1) * 4;
                float4v v = acc[mt][nt];
                u16 t0 = f2bf(v[0] + bval), t1 = f2bf(v[1] + bval);
                u16 t2 = f2bf(v[2] + bval), t3 = f2bf(v[3] + bval);
                uint2 pk = make_uint2((u32)t0 | ((u32)t1 << 16),
                                      (u32)t2 | ((u32)t3 << 16));
                *(uint2*)&stg[rl * 64 + ((g ^ rx) << 3) + b0] = pk;
            }
        }
        asm volatile("s_waitcnt lgkmcnt(0)" ::: "memory");
        __syncthreads();
        int bbi = (mBase + wr) >> 11;
        int tt0 = (mBase + wr) & 2047;
        #pragma unroll
        for (int i = 0; i < 8; i++) {
            int rl = i * 8 + (lane >> 3);                 // d_local
            int c8 = lane & 7;                            // t-granule
            short8 s = *(const short8*)&stg[rl * 64 + ((c8 ^ (rl & 7)) << 3)];
            *(uint4*)&Vt_out[((size_t)bbi * 512 + nBase + wc + rl) * 2048 +
                             tt0 + c8 * 8] = *(uint4*)&s;
        }
    } else {
        u16* dst = (z == 0) ? Qo : Ko;
        #pragma unroll
        for (int nt = 0; nt < 4; nt++) {
            int cl = nt * 16 + l16;
            float bval = bf2f(bias[nBase + wc + cl]);
            int g = nt * 2 + (l16 >> 3);
            int b = l16 & 7;
            #pragma unroll
            for (int mt = 0; mt < 4; mt++) {
                float4v v = acc[mt][nt];
                #pragma unroll
                for (int r = 0; r < 4; r++) {
                    int rl = mt * 16 + quad * 4 + r;
                    stg[rl * 64 + ((g ^ (rl & 7)) << 3) + b] = f2bf(v[r] + bval);
                }
            }
        }
        asm volatile("s_waitcnt lgkmcnt(0)" ::: "memory");
        __syncthreads();
        #pragma unroll
        for (int i = 0; i < 8; i++) {
            int rl = i * 8 + (lane >> 3);                 // m_local
            int c8 = lane & 7;                            // n-granule
            short8 s = *(const short8*)&stg[rl * 64 + ((c8 ^ (rl & 7)) << 3)];
            *(uint4*)&dst[(size_t)(mBase + wr + rl) * 512 +
                          nBase + wc + c8 * 8] = *(uint4*)&s;
        }
    }
#undef PISSUE
#undef XSB
#undef WSB
}

// ---------------- Kernel 5: flash attention (defer-max v2 + deferred l) -----
// 256 VGPR -- at the allocation ceiling with zero slack (v9/v12/v19 law).
// lrow holds per-lane PARTIAL sums in-loop; butterfly once in epilogue.

#define LOADK(dst, kB, half)                                                  \
    { _Pragma("unroll")                                                       \
      for (int j = 0; j < 8; j++) {                                           \
        int row2 = 2 * (j * 4 + w);                                           \
        int row = row2 + (lane >> 5);                                         \
        int col8 = lane & 31;                                                 \
        GLD16(&Kb[(size_t)((kB) + row) * 512 + (half) * 256 +                 \
                  ((col8 ^ (row & 7)) << 3)], &dst[row2 * 256]);              \
      } }

#define LOADV(dst, kB, half)                                                  \
    { _Pragma("unroll")                                                       \
      for (int j = 0; j < 8; j++) {                                           \
        int blk8 = 8 * (j * 4 + w);                                           \
        int dl = blk8 + (lane >> 3);                                          \
        int col8 = lane & 7;                                                  \
        GLD16(&Vb[(size_t)((half) * 256 + dl) * 2048 + (kB) +                 \
                  ((col8 ^ (dl & 7)) << 3)], &dst[blk8 * 64]);                \
      } }

#define SSTEP(buf, h)                                                         \
    { _Pragma("unroll")                                                       \
      for (int kk = 0; kk < 8; kk++) {                                        \
        _Pragma("unroll")                                                     \
        for (int nt = 0; nt < 4; nt++) {                                      \
          short8 bf = *(const short8*)&buf[(nt * 16 + l16) * 256 +            \
                                           (((kk * 4 + quad) ^ sw) << 3)];    \
          accS[nt] = mfma16(qf[(h) * 8 + kk], bf, accS[nt]);                  \
        } } }

#define PVSTEP(buf, accO)                                                     \
    { _Pragma("unroll")                                                       \
      for (int kk = 0; kk < 2; kk++) {                                        \
        _Pragma("unroll")                                                     \
        for (int dt = 0; dt < 4; dt++) {                                      \
          int rowv = w * 64 + dt * 16 + l16;                                  \
          short8 bf = *(const short8*)&buf[rowv * 64 +                        \
                                           (((kk * 4 + quad) ^ sw) << 3)];    \
          _Pragma("unroll")                                                   \
          for (int mt = 0; mt < 4; mt++)                                      \
            accO[dt][mt] = mfma16(pf[mt][kk], bf, accO[dt][mt]);              \
        } } }

__global__ __launch_bounds__(256, 1) void attn_k(
        const u16* __restrict__ Q, const u16* __restrict__ K,
        const u16* __restrict__ Vt, const int* __restrict__ flag,
        void* __restrict__ out, u16* __restrict__ Opart,
        float2* __restrict__ ml, int dosplit) {
    int blk = blockIdx.x;
    int b, qt, h, kt0, kt1;
    if (dosplit) {
        qt = (blk < 256) ? (31 - (blk >> 4)) : ((blk - 256) >> 4);
        h  = (blk >> 3) & 1;
        b  = blk & 7;
        int n = qt + 1, mid = n >> 1;
        kt0 = h ? mid : 0;
        kt1 = h ? n : mid;
    } else {
        qt = 31 - (blk >> 3);
        h  = 0;
        b  = blk & 7;
        kt0 = 0; kt1 = qt + 1;
    }
    int q0 = qt * 64;
    int isbf = flag[0];

    __shared__ __attribute__((aligned(16))) u16 KV0[16384];   // 32 KB
    __shared__ __attribute__((aligned(16))) u16 KV1[16384];   // 32 KB
    __shared__ __attribute__((aligned(16))) u16 Ps[4096];     // P 64x64 bf16
    __shared__ float al_s[64];
    __shared__ float il_s[64];
    __shared__ int skip_s[4];

    int tid = threadIdx.x;
    int w = tid >> 6, lane = tid & 63, quad = lane >> 4, l16 = lane & 15;
    int sw = l16 & 7;

    const u16* Qb = Q  + (size_t)b * 2048 * 512;
    const u16* Kb = K  + (size_t)b * 2048 * 512;
    const u16* Vb = Vt + (size_t)b * 512 * 2048;

    if (kt0 < kt1) LOADK(KV0, kt0 * 64, 0);    // prefetch first K half0

    // Q fragments in regs: rows w*16+l16, qf[g] = d-granule g (static idx only)
    short8 qf[16];
    {
        const u16* Qrow = &Qb[(size_t)(q0 + w * 16 + l16) * 512];
        #pragma unroll
        for (int g = 0; g < 16; g++)
            qf[g] = *(const short8*)&Qrow[g * 32 + quad * 8];
    }

    float4v accO0[4][4] = {};     // d = 0*256 + w*64 + dt*16 + l16
    float4v accO1[4][4] = {};     // d = 1*256 + w*64 + dt*16 + l16
    float4v accS[4] = {};         // keys nt*16+l16, rows w*16+quad*4+r
    short8 pf[4][2];
    float mrow[4] = {-1e30f, -1e30f, -1e30f, -1e30f};
    float lrow[4] = {0.f, 0.f, 0.f, 0.f};   // per-lane partial sums
    const float scale = 0.044194173824159216f;     // 1/sqrt(512)

    __syncthreads();

    for (int kt = kt0; kt < kt1; kt++) {
        int kB = kt * 64;

        // ---- ph0: prefetch K half1 -> KV1; S += Q0.K0 from KV0 ----
        LOADK(KV1, kB, 1);
        SSTEP(KV0, 0);
        __syncthreads();

        // ---- ph1: prefetch V half0 -> KV0; S += Q1.K1 from KV1; softmax ----
        LOADV(KV0, kB, 0);
        SSTEP(KV1, 1);
        {
            int diag = (kt == qt);
            float pv[4][4], lmx[4], alpha[4];
            #pragma unroll
            for (int r = 0; r < 4; r++) {
                float mx = -1e30f;
                #pragma unroll
                for (int nt = 0; nt < 4; nt++) {
                    float sv = accS[nt][r] * scale;
                    if (diag && (nt * 16 + l16 > w * 16 + quad * 4 + r)) sv = -1e30f;
                    pv[nt][r] = sv;
                    mx = fmaxf(mx, sv);
                }
                lmx[r] = mx;
            }
            // defer-max (T13) v2: decide from lane-local maxes (no shuffles);
            // reduce only on the rare non-skip path (wave-uniform branch).
            int small = (lmx[0] - mrow[0] <= 8.f) && (lmx[1] - mrow[1] <= 8.f) &&
                        (lmx[2] - mrow[2] <= 8.f) && (lmx[3] - mrow[3] <= 8.f);
            int wskip = __all(small) ? 1 : 0;
            if (lane == 0) skip_s[w] = wskip;
            if (wskip) {
                #pragma unroll
                for (int r = 0; r < 4; r++) alpha[r] = 1.0f;
            } else {
                #pragma unroll
                for (int r = 0; r < 4; r++) {
                    float mx = lmx[r];
                    mx = fmaxf(mx, __shfl_xor(mx, 1));
                    mx = fmaxf(mx, __shfl_xor(mx, 2));
                    mx = fmaxf(mx, __shfl_xor(mx, 4));
                    mx = fmaxf(mx, __shfl_xor(mx, 8));
                    float mnew = fmaxf(mrow[r], mx);
                    alpha[r] = __expf(mrow[r] - mnew);
                    mrow[r] = mnew;
                }
            }
            // lrow = per-lane partial (sum of this lane's 4 columns);
            // cross-lane butterfly deferred to the epilogue.
            #pragma unroll
            for (int r = 0; r < 4; r++) {
                float sum = 0.f;
                #pragma unroll
                for (int nt = 0; nt < 4; nt++) {
                    pv[nt][r] = __expf(pv[nt][r] - mrow[r]);
                    sum += pv[nt][r];
                }
                lrow[r] = lrow[r] * alpha[r] + sum;
            }
            #pragma unroll
            for (int nt = 0; nt < 4; nt++)
                #pragma unroll
                for (int r = 0; r < 4; r++)
                    Ps[(w * 16 + quad * 4 + r) * 64 + nt * 16 + l16] = f2bf(pv[nt][r]);
            #pragma unroll
            for (int r = 0; r < 4; r++) al_s[w * 16 + quad * 4 + r] = alpha[r];
            #pragma unroll
            for (int nt = 0; nt < 4; nt++) accS[nt] = (float4v){0.f, 0.f, 0.f, 0.f};
        }
        __syncthreads();

        // ---- ph2: prefetch V half1 -> KV1; P-frags (+rescale unless all
        //          waves deferred); O0 += P.V0 ----
        LOADV(KV1, kB, 1);
        {
            #pragma unroll
            for (int mt = 0; mt < 4; mt++)
                #pragma unroll
                for (int kk = 0; kk < 2; kk++)
                    pf[mt][kk] = *(const short8*)&Ps[(mt * 16 + l16) * 64 +
                                                     kk * 32 + quad * 8];
            int bskip = skip_s[0] & skip_s[1] & skip_s[2] & skip_s[3];
            if (!bskip) {
                float alf[4][4];
                #pragma unroll
                for (int mt = 0; mt < 4; mt++)
                    #pragma unroll
                    for (int r = 0; r < 4; r++)
                        alf[mt][r] = al_s[mt * 16 + quad * 4 + r];
                #pragma unroll
                for (int dt = 0; dt < 4; dt++)
                    #pragma unroll
                    for (int mt = 0; mt < 4; mt++)
                        #pragma unroll
                        for (int r = 0; r < 4; r++) {
                            accO0[dt][mt][r] *= alf[mt][r];
                            accO1[dt][mt][r] *= alf[mt][r];
                        }
            }
        }
        PVSTEP(KV0, accO0);
        __syncthreads();

        // ---- ph3: prefetch next K half0 -> KV0; O1 += P.V1 from KV1 ----
        if (kt + 1 < kt1) LOADK(KV0, kB + 64, 0);
        PVSTEP(KV1, accO1);
        __syncthreads();
    }

    // finalize lrow -- one butterfly over the 16-lane group.
    #pragma unroll
    for (int r = 0; r < 4; r++) {
        lrow[r] += __shfl_xor(lrow[r], 1);
        lrow[r] += __shfl_xor(lrow[r], 2);
        lrow[r] += __shfl_xor(lrow[r], 4);
        lrow[r] += __shfl_xor(lrow[r], 8);
    }

    if (dosplit) {
        // ---- epilogue A: write unnormalized O (bf16) + per-row (m,l) ----
        if (l16 == 0) {
            #pragma unroll
            for (int r = 0; r < 4; r++) {
                int grow = b * 2048 + q0 + w * 16 + quad * 4 + r;
                ml[h * 16384 + grow] = make_float2(mrow[r], lrow[r]);
            }
        }
        #pragma unroll
        for (int dt = 0; dt < 4; dt++) {
            int dg = w * 64 + dt * 16 + l16;
            #pragma unroll
            for (int mt = 0; mt < 4; mt++)
                #pragma unroll
                for (int r = 0; r < 4; r++) {
                    int grow = b * 2048 + q0 + mt * 16 + quad * 4 + r;
                    size_t base = ((size_t)h * 16384 + grow) * 512;
                    Opart[base + dg]       = f2bf(accO0[dt][mt][r]);
                    Opart[base + dg + 256] = f2bf(accO1[dt][mt][r]);
                }
        }
    } else {
        // ---- epilogue B: share 1/l, normalize, write out[..., 512:1024] ----
        #pragma unroll
        for (int r = 0; r < 4; r++) il_s[w * 16 + quad * 4 + r] = 1.0f / lrow[r];
        __syncthreads();
        float invl[4][4];
        #pragma unroll
        for (int mt = 0; mt < 4; mt++)
            #pragma unroll
            for (int r = 0; r < 4; r++) invl[mt][r] = il_s[mt * 16 + quad * 4 + r];
        u16*   o16 = (u16*)out;
        float* o32 = (float*)out;
        #pragma unroll
        for (int dt = 0; dt < 4; dt++) {
            int dg0 = 512 + w * 64 + dt * 16 + l16;
            #pragma unroll
            for (int mt = 0; mt < 4; mt++)
                #pragma unroll
                for (int r = 0; r < 4; r++) {
                    int rowg = q0 + mt * 16 + quad * 4 + r;
                    size_t base = ((size_t)b * 2048 + rowg) * 1024;
                    float v0 = accO0[dt][mt][r] * invl[mt][r];
                    float v1 = accO1[dt][mt][r] * invl[mt][r];
                    if (isbf) {
                        o16[base + dg0]       = f2bf(v0);
                        o16[base + dg0 + 256] = f2bf(v1);
                    } else {
                        o32[base + dg0]       = v0;
                        o32[base + dg0 + 256] = v1;
                    }
                }
        }
    }
}

// ---------------- Kernel 6: split-K combine ---------------------------------
__global__ __launch_bounds__(256) void combine_k(
        const u16* __restrict__ Opart, const float2* __restrict__ ml,
        const int* __restrict__ flag, void* __restrict__ out) {
    int tid = threadIdx.x;
    int grow = blockIdx.x * 4 + (tid >> 6);
    int d0 = (tid & 63) * 8;
    float2 ml0 = ml[grow], ml1 = ml[16384 + grow];
    float m = fmaxf(ml0.x, ml1.x);
    float a0 = __expf(ml0.x - m), a1 = __expf(ml1.x - m);
    float il = 1.0f / (ml0.y * a0 + ml1.y * a1);
    a0 *= il; a1 *= il;
    uint4 v0 = *(const uint4*)&Opart[(size_t)grow * 512 + d0];
    uint4 v1 = *(const uint4*)&Opart[(size_t)(16384 + grow) * 512 + d0];
    const u16* u0 = (const u16*)&v0;
    const u16* u1 = (const u16*)&v1;
    float res[8];
    #pragma unroll
    for (int i = 0; i < 8; i++)
        res[i] = bf2f(u0[i]) * a0 + bf2f(u1[i]) * a1;
    size_t base = (size_t)grow * 1024 + 512 + d0;
    if (flag[0]) {
        union { u16 us[8]; uint4 v; } pk;
        #pragma unroll
        for (int i = 0; i < 8; i++) pk.us[i] = f2bf(res[i]);
        *(uint4*)((u16*)out + base) = pk.v;
    } else {
        float* o = (float*)out + base;
        *(float4*)o = make_float4(res[0], res[1], res[2], res[3]);
        *(float4*)(o + 4) = make_float4(res[4], res[5], res[6], res[7]);
    }
}

// ---------------- launcher --------------------------------------------------
extern "C" void kernel_launch(void* const* d_in, const int* in_sizes, int n_in,
                              void* d_out, int out_size, void* d_ws, size_t ws_size,
                              hipStream_t stream) {
    const void* x  = d_in[0];
    const void* Wq = d_in[1];
    const void* bq = d_in[2];
    const void* Wk = d_in[3];
    const void* bk = d_in[4];
    const void* Wv = d_in[5];
    const void* bv = d_in[6];

    u16* base = (u16*)d_ws;
    int* flag = (int*)base;                         // 16 B
    u16* Wt   = base + 8;                           // 3*512*512
    u16* bb   = Wt + 786432;                        // 1536 (pad 1544)
    u16* xb   = bb + 1544;                          // 8,388,608
    u16* Qw   = xb + 8388608;
    u16* Kw   = Qw + 8388608;
    u16* Vtw  = Kw + 8388608;                       // Vt[b][d][t]
    u16* Opart = Vtw + 8388608;                     // 2*16384*512 u16 = 33.5 MB
    float2* mlb = (float2*)(Opart + 16777216);      // 2*16384 float2 = 256 KB

    size_t need = ((size_t)(Opart - base) + 16777216) * 2 + 262144;
    int dosplit = (ws_size >= need) ? 1 : 0;

    hipLaunchKernelGGL(prep_k, dim3(4294), dim3(256), 0, stream,
                       x, Wq, Wk, Wv, bq, bk, bv, flag, xb, d_out, Wt, bb);
    hipLaunchKernelGGL(proj_k, dim3(1536), dim3(256), 0, stream, xb, Wt, bb, Qw, Kw, Vtw);
    if (dosplit) {
        hipLaunchKernelGGL(attn_k, dim3(512), dim3(256), 0, stream,
                           Qw, Kw, Vtw, flag, d_out, Opart, mlb, 1);
        hipLaunchKernelGGL(combine_k, dim3(4096), dim3(256), 0, stream,
                           Opart, mlb, flag, d_out);
    } else {
        hipLaunchKernelGGL(attn_k, dim3(256), dim3(256), 0, stream,
                           Qw, Kw, Vtw, flag, d_out, Opart, mlb, 0);
    }
}